// Round 5
// baseline (300.493 us; speedup 1.0000x reference)
//
#include <hip/hip_runtime.h>
#include <type_traits>

#define DIMC 512
#define NTOK 4097
#define GH 64
#define GW 64
#define TH 4    // output rows per thread
#define WT 8    // output cols per thread (halves ds_read + halo per output)

// Compile-time-for: every array index is a template constant -> SROA promotes.
template <int I, int N, typename F>
__device__ __forceinline__ void static_for(F&& f)
{
    if constexpr (I < N) {
        f(std::integral_constant<int, I>{});
        static_for<I + 1, N>(f);
    }
}

// Fold w7 + padded(w5) + padded(w3) + identity into one 7x7 depthwise kernel
// (tap-major [t][c]), bias = b7+b5+b3, AND the cls-token pass-through copy
// (merged here to save a launch).
__global__ __launch_bounds__(256) void prep_kernel(
    const float* __restrict__ x,
    const float* __restrict__ w7, const float* __restrict__ b7,
    const float* __restrict__ w5, const float* __restrict__ b5,
    const float* __restrict__ w3, const float* __restrict__ b3,
    float* __restrict__ wc, float* __restrict__ bc,
    float* __restrict__ out)
{
    int idx = blockIdx.x * 256 + threadIdx.x;   // 0 .. 33279
    if (idx < DIMC * 49) {
        int c = idx & (DIMC - 1);
        int t = idx >> 9;
        int dy = t / 7, dx = t - dy * 7;
        float v = w7[c * 49 + t];
        if (dy >= 1 && dy <= 5 && dx >= 1 && dx <= 5)
            v += w5[c * 25 + (dy - 1) * 5 + (dx - 1)];
        if (dy >= 2 && dy <= 4 && dx >= 2 && dx <= 4)
            v += w3[c * 9 + (dy - 2) * 3 + (dx - 2)];
        if (dy == 3 && dx == 3) v += 1.0f;      // identity (residual) term
        wc[t * DIMC + c] = v;
    }
    if (idx < DIMC) bc[idx] = b7[idx] + b5[idx] + b3[idx];
    int cidx = idx - DIMC * 49;                 // cls token copy: 16*512 floats
    if (cidx >= 0 && cidx < 16 * DIMC) {
        int b = cidx >> 9, c = cidx & 511;
        size_t off = (size_t)b * NTOK * DIMC + c;
        out[off] = x[off];
    }
}

// Depthwise combined 7x7 conv, channels on lanes, <=64..96 VGPR design.
// Weights in LDS, layout [dy][half][lane][4]: one weight row = 2 ds_read_b128
// at (lane*16 + imm) — fully contiguous 1024B/wave, conflict-free, zero VALU.
// Round-4 profile: 196 ds_read_b32/thread (~60us LDS pipe) + guard/addressing
// VALU were the gap to the HBM floor; WT=8 + b128 cuts ds_reads 12.25 ->
// 1.75/output and halo loads 6.25 -> 4.375/output. FMA/output unchanged (49).
__global__ __launch_bounds__(256) void dwconv_kernel(
    const float* __restrict__ x, const float* __restrict__ wc,
    const float* __restrict__ bc, float* __restrict__ out)
{
    __shared__ __align__(16) float wt_lds[7 * 2 * 256];  // 14 KiB

    const int lane  = threadIdx.x;                 // 0..63 (lane = channel)
    const int wtile = threadIdx.y;                 // 0..3 (wave-uniform)
    const int cs    = blockIdx.x;                  // 0..1 col segment (32 cols)
    const int rs    = blockIdx.y & 15;             // row tile (4 rows)
    const int cg    = blockIdx.y >> 4;             // channel group 0..7
    const int b     = blockIdx.z;                  // 0..15
    const int cc    = (cg << 6) + lane;            // channel 0..511
    const int h0    = rs * TH;                     // output row base
    const int w0    = cs * 32 + wtile * WT;        // output col base (wave-uniform)

    // Stage folded weights: chunk = dy*2+h holds taps dy*7 + h*4 + q (q=0..3),
    // laid out [chunk][lane][q]; tap 7 of each row is zero padding.
    for (int idx = wtile * 64 + lane; idx < 7 * 2 * 256; idx += 256) {
        int chunk = idx >> 8, within = idx & 255;
        int l = within >> 2, q = within & 3;
        int dy = chunk >> 1, tap = (chunk & 1) * 4 + q;
        wt_lds[idx] = (tap < 7) ? wc[(dy * 7 + tap) * DIMC + (cg << 6) + l] : 0.0f;
    }
    __syncthreads();

    const float bias = bc[cc];
    const float* __restrict__ xin = x   + ((size_t)b * NTOK + 1) * DIMC + cc;
    float* __restrict__ op        = out + ((size_t)b * NTOK + 1) * DIMC + cc;

    float acc[TH][WT];

    static_for<0, TH + 6>([&](auto iC) {
        constexpr int i = decltype(iC)::value;     // input row r = h0-3+i
        const int r = h0 + (i - 3);

        // --- load one input row (WT+6 coalesced 256B/wave loads) ---
        float row[WT + 6];
        if (r >= 0 && r < GH) {                    // wave-uniform guard
            const float* __restrict__ rp = xin + (size_t)r * (GW * DIMC);
            static_for<0, WT + 6>([&](auto jC) {
                constexpr int j = decltype(jC)::value;
                const int col = w0 - 3 + j;        // wave-uniform guard
                row[j] = (col >= 0 && col < GW) ? rp[(size_t)col * DIMC] : 0.0f;
            });
        } else {
            static_for<0, WT + 6>([&](auto jC) {
                row[decltype(jC)::value] = 0.0f;
            });
        }

        // --- scatter into the <=TH open output rows: k = i - dy ---
        static_for<0, 7>([&](auto dyC) {
            constexpr int dy = decltype(dyC)::value;
            constexpr int k  = i - dy;
            if constexpr (k >= 0 && k < TH) {
                const float4 wa = *reinterpret_cast<const float4*>(
                    &wt_lds[(dy * 2 + 0) * 256 + (lane << 2)]);
                const float4 wb = *reinterpret_cast<const float4*>(
                    &wt_lds[(dy * 2 + 1) * 256 + (lane << 2)]);
                const float wr[7] = {wa.x, wa.y, wa.z, wa.w, wb.x, wb.y, wb.z};
                static_for<0, WT>([&](auto tC) {
                    constexpr int t = decltype(tC)::value;
                    float a = (dy == 0) ? bias : acc[k][t];
#pragma unroll
                    for (int dx = 0; dx < 7; ++dx)
                        a = fmaf(wr[dx], row[t + dx], a);
                    acc[k][t] = a;
                });
            }
        });

        // --- output row k = i-6 is complete ---
        if constexpr (i >= 6) {
            constexpr int k = i - 6;
            static_for<0, WT>([&](auto tC) {
                constexpr int t = decltype(tC)::value;
                op[((size_t)(h0 + k) * GW + (w0 + t)) * DIMC] = acc[k][t];
            });
        }
    });
}

extern "C" void kernel_launch(void* const* d_in, const int* in_sizes, int n_in,
                              void* d_out, int out_size, void* d_ws, size_t ws_size,
                              hipStream_t stream)
{
    const float* x  = (const float*)d_in[0];
    const float* w7 = (const float*)d_in[1];
    const float* b7 = (const float*)d_in[2];
    const float* w5 = (const float*)d_in[3];
    const float* b5 = (const float*)d_in[4];
    const float* w3 = (const float*)d_in[5];
    const float* b3 = (const float*)d_in[6];
    float* out = (float*)d_out;
    float* wcomb = (float*)d_ws;            // 49*512 floats
    float* bcomb = wcomb + 49 * DIMC;       // 512 floats

    // weights fold + bias + cls copy, one launch (33280 threads)
    prep_kernel<<<130, 256, 0, stream>>>(x, w7, b7, w5, b5, w3, b3,
                                         wcomb, bcomb, out);

    // grid: colseg(2) x (rowtile(16) + 16*cgroup(8)) x batch(16) = 4096 blocks
    dim3 grid(2, 128, 16);
    dim3 block(64, 4, 1);
    dwconv_kernel<<<grid, block, 0, stream>>>(x, wcomb, bcomb, out);
}